// Round 13
// baseline (226.593 us; speedup 1.0000x reference)
//
#include <hip/hip_runtime.h>
#include <hip/hip_bf16.h>

constexpr int BH  = 32;     // B*H
constexpr int LQ  = 1024;
constexpr int DK  = 512;
constexpr float SCALE = 0.04419417382415922f;  // 1/sqrt(512)

using short8 = __attribute__((ext_vector_type(8))) short;
using f32x4  = __attribute__((ext_vector_type(4))) float;

__device__ __forceinline__ unsigned short cvt_bf16(float x) {
  unsigned int u = __builtin_bit_cast(unsigned int, x);
  u += 0x7FFFu + ((u >> 16) & 1u);   // RNE
  return (unsigned short)(u >> 16);
}
__device__ __forceinline__ float bf2f(unsigned short s) {
  return __builtin_bit_cast(float, (unsigned int)s << 16);
}
// HW packed fp32->bf16 (RNE), non-volatile (schedulable).
__device__ __forceinline__ unsigned int pkbf(float lo, float hi) {
  unsigned int r;
  asm("v_cvt_pk_bf16_f32 %0, %1, %2" : "=v"(r) : "v"(lo), "v"(hi));
  return r;
}

// async global->LDS, 16B per lane. LDS dest must be wave-uniform (HW adds lane*16).
__device__ __forceinline__ void lds_load16(const void* g, void* l) {
  __builtin_amdgcn_global_load_lds(
      (const __attribute__((address_space(1))) unsigned int*)g,
      (__attribute__((address_space(3))) unsigned int*)l, 16, 0, 0);
}

// ---------------------------------------------------------------------------
// qk_v6: P' = exp(scale*Q.K^T) masked->0 (bf16) + per-row partial sums.
// Reads Q,K fp32 DIRECTLY via global_load_lds (no cvt pre-pass, 0 VGPR
// staging cost). BK=32 keeps LDS at 48KB (A 256x128B fp32 + B 128x128B) ->
// 3 blocks/CU. fp32->bf16 conversion happens on the LDS->fragment path:
// 2x ds_read_b128 + 4x v_cvt_pk_bf16_f32 per fragment.
// Tile 256(M) x 128(N), 8 waves (4M x 2N), grid 1024 blocks.
// ---------------------------------------------------------------------------
__global__ __launch_bounds__(512) void qk_v6_kernel(
    const float* __restrict__ Q, const float* __restrict__ K,
    const int* __restrict__ mask, unsigned short* __restrict__ P,
    float* __restrict__ partials) {
  __shared__ __attribute__((aligned(16))) unsigned short smem[24576];  // 49152 B

  // XCD-aware bijective swizzle (NWG = 8*4*32 = 1024, %8==0)
  int flat = blockIdx.x + 8 * (blockIdx.y + 4 * blockIdx.z);
  flat = (flat % 8) * 128 + flat / 8;
  const int bx = flat % 8;            // N tile (128 cols)
  const int by = (flat / 8) % 4;      // M tile (256 rows)
  const int bh = flat / 32;

  const int t = threadIdx.x;          // 0..511
  const int lane = t & 63, wave = t >> 6;
  const int wr = wave >> 1;           // 0..3 (64-row band)
  const int wc = wave & 1;            // 0..1 (64-col band)
  const int fr = lane & 15, fq = lane >> 4;
  const int m0 = by * 256, n0 = bx * 128;

  // fp32 rows: 2048 B row stride
  const char* Ab = (const char*)(Q + ((size_t)bh * LQ + m0) * DK);
  const char* Bb = (const char*)(K + ((size_t)bh * LQ + n0) * DK);

  // mask dtype detection (uniform)
  unsigned int orv = 0;
  {
    const unsigned int* mw = (const unsigned int*)mask;
    #pragma unroll
    for (int i = 0; i < 64; ++i) orv |= mw[i];
  }
  const bool byteMode = (orv > 1u);

  f32x4 acc[4][4];
  #pragma unroll
  for (int i = 0; i < 4; ++i)
    #pragma unroll
    for (int j = 0; j < 4; ++j) acc[i][j] = (f32x4){0.f, 0.f, 0.f, 0.f};

  char* const AsB = (char*)smem;            // A fp32: 32768 B (256 rows x 128B)
  char* const BsB = (char*)smem + 32768;    // B fp32: 16384 B (128 rows x 128B)

  for (int kt = 0; kt < 16; ++kt) {
    const int kb = kt * 128;    // byte offset of 32-col fp32 window in 2048B row
    __syncthreads();
    // stage A (4 issues) + B (2 issues); swizzled fp32 source -> linear LDS
    #pragma unroll
    for (int i = 0; i < 4; ++i) {
      const int p  = i * 8192 + t * 16;
      const int r  = p >> 7;                 // row 0..255 (128B rows)
      const int ch = (p >> 4) & 7;
      lds_load16(Ab + (size_t)r * 2048 + kb + ((ch ^ (r & 7)) << 4),
                 AsB + i * 8192 + wave * 1024);
    }
    #pragma unroll
    for (int i = 0; i < 2; ++i) {
      const int p  = i * 8192 + t * 16;
      const int r  = p >> 7;                 // row 0..127
      const int ch = (p >> 4) & 7;
      lds_load16(Bb + (size_t)r * 2048 + kb + ((ch ^ (r & 7)) << 4),
                 BsB + i * 8192 + wave * 1024);
    }
    __syncthreads();

    // fragments: 8 fp32 k-elems = chunks {2fq, 2fq+1} (each XOR row-swizzled)
    short8 a[4], b[4];
    #pragma unroll
    for (int mi = 0; mi < 4; ++mi) {
      const int r = wr * 64 + mi * 16 + fr;            // 0..255
      const float4 x = *(const float4*)(AsB + r * 128 + (((2 * fq)     ^ (r & 7)) << 4));
      const float4 y = *(const float4*)(AsB + r * 128 + (((2 * fq + 1) ^ (r & 7)) << 4));
      unsigned int w[4] __attribute__((aligned(16)));
      w[0] = pkbf(x.x, x.y); w[1] = pkbf(x.z, x.w);
      w[2] = pkbf(y.x, y.y); w[3] = pkbf(y.z, y.w);
      a[mi] = *(short8*)w;
    }
    #pragma unroll
    for (int ni = 0; ni < 4; ++ni) {
      const int r = wc * 64 + ni * 16 + fr;            // 0..127
      const float4 x = *(const float4*)(BsB + r * 128 + (((2 * fq)     ^ (r & 7)) << 4));
      const float4 y = *(const float4*)(BsB + r * 128 + (((2 * fq + 1) ^ (r & 7)) << 4));
      unsigned int w[4] __attribute__((aligned(16)));
      w[0] = pkbf(x.x, x.y); w[1] = pkbf(x.z, x.w);
      w[2] = pkbf(y.x, y.y); w[3] = pkbf(y.z, y.w);
      b[ni] = *(short8*)w;
    }
    #pragma unroll
    for (int mi = 0; mi < 4; ++mi)
      #pragma unroll
      for (int ni = 0; ni < 4; ++ni)
        acc[mi][ni] = __builtin_amdgcn_mfma_f32_16x16x32_bf16(a[mi], b[ni], acc[mi][ni], 0, 0, 0);
  }

  // ---- epilogue in two 128-row halves (C-stage aliases staging LDS) ----
  unsigned short* Cs = smem;   // [128][136] bf16 = 34816 B
  const size_t pbase = (size_t)bh * LQ * LQ;
  #pragma unroll
  for (int h = 0; h < 2; ++h) {
    __syncthreads();
    if ((wr >> 1) == h) {
      #pragma unroll
      for (int mi = 0; mi < 4; ++mi)
        #pragma unroll
        for (int ni = 0; ni < 4; ++ni) {
          const int col = wc * 64 + ni * 16 + fr;
          #pragma unroll
          for (int r = 0; r < 4; ++r) {
            const int rloc = (wr & 1) * 64 + mi * 16 + fq * 4 + r;
            Cs[rloc * 136 + col] = cvt_bf16(__expf(acc[mi][ni][r] * SCALE));
          }
        }
    }
    __syncthreads();
    const int rl = t >> 4;          // 0..31
    const int cl = (t & 15) * 8;    // 0..120
    #pragma unroll
    for (int rb = 0; rb < 4; ++rb) {
      const int rloc = rb * 32 + rl;
      const int rg   = m0 + h * 128 + rloc;
      const size_t gidx = pbase + (size_t)rg * LQ + (n0 + cl);
      short8 sv = *(const short8*)&Cs[rloc * 136 + cl];
      bool mk[8];
      if (byteMode) {
        const unsigned char* mb = (const unsigned char*)mask + gidx;
        uint2 w = *(const uint2*)mb;
        #pragma unroll
        for (int j = 0; j < 4; ++j) mk[j]     = ((w.x >> (8 * j)) & 255u) != 0u;
        #pragma unroll
        for (int j = 0; j < 4; ++j) mk[4 + j] = ((w.y >> (8 * j)) & 255u) != 0u;
      } else {
        int4 w0 = *(const int4*)(mask + gidx);
        int4 w1 = *(const int4*)(mask + gidx + 4);
        mk[0] = w0.x != 0; mk[1] = w0.y != 0; mk[2] = w0.z != 0; mk[3] = w0.w != 0;
        mk[4] = w1.x != 0; mk[5] = w1.y != 0; mk[6] = w1.z != 0; mk[7] = w1.w != 0;
      }
      unsigned short out[8] __attribute__((aligned(16)));
      float s = 0.f;
      #pragma unroll
      for (int j = 0; j < 8; ++j) {
        unsigned short v = mk[j] ? (unsigned short)0 : (unsigned short)sv[j];
        out[j] = v;
        s += bf2f(v);
      }
      *(short8*)(P + gidx) = *(short8*)out;
      s += __shfl_xor(s, 1); s += __shfl_xor(s, 2);
      s += __shfl_xor(s, 4); s += __shfl_xor(s, 8);
      if ((t & 15) == 0)
        partials[((size_t)bh * LQ + rg) * 8 + bx] = s;
    }
  }
}

// ---------------------------------------------------------------------------
// attn_fin: attn[row][col] = P'[row][col] * (1/rowsum)  (bf16 -> fp32)
// ---------------------------------------------------------------------------
__global__ __launch_bounds__(256) void attn_fin(
    const unsigned short* __restrict__ P, const float* __restrict__ partials,
    float* __restrict__ attn) {
  const int ch = blockIdx.x, rb64 = blockIdx.y, bh = blockIdx.z;
  const int m0 = rb64 * 64;
  __shared__ float invs[64];
  const int t = threadIdx.x;
  if (t < 64) {
    const float* pp = partials + ((size_t)bh * LQ + m0 + t) * 8;
    float s = ((pp[0] + pp[1]) + (pp[2] + pp[3])) + ((pp[4] + pp[5]) + (pp[6] + pp[7]));
    invs[t] = 1.0f / s;
  }
  __syncthreads();
  const size_t pbase = (size_t)bh * LQ * LQ;
  const int c0 = ch * 512;
  #pragma unroll
  for (int rb = 0; rb < 4; ++rb) {
    const int rloc = rb * 16 + (t >> 4);
    const int row  = m0 + rloc;
    const float inv = invs[rloc];
    const size_t base = pbase + (size_t)row * LQ + c0 + (t & 15) * 8;
    #pragma unroll
    for (int j = 0; j < 4; ++j) {
      short8 sv = *(const short8*)(P + base + j * 128);
      float4 o0, o1;
      o0.x = bf2f((unsigned short)sv[0]) * inv;
      o0.y = bf2f((unsigned short)sv[1]) * inv;
      o0.z = bf2f((unsigned short)sv[2]) * inv;
      o0.w = bf2f((unsigned short)sv[3]) * inv;
      o1.x = bf2f((unsigned short)sv[4]) * inv;
      o1.y = bf2f((unsigned short)sv[5]) * inv;
      o1.z = bf2f((unsigned short)sv[6]) * inv;
      o1.w = bf2f((unsigned short)sv[7]) * inv;
      *(float4*)(attn + base + j * 128)     = o0;
      *(float4*)(attn + base + j * 128 + 4) = o1;
    }
  }
}

// ---------------------------------------------------------------------------
// pv2: ctx = (P' . V) * invrow.  Single LDS buffer + T14 split (round-12
// proven): V loads for k+1 issued before the barrier; pack+write after it.
// ---------------------------------------------------------------------------
__global__ __launch_bounds__(256) void pv2_kernel(
    const unsigned short* __restrict__ P, const float* __restrict__ V,
    const float* __restrict__ partials, float* __restrict__ O) {
  __shared__ __attribute__((aligned(16))) unsigned short As[8192];        // 16KB
  __shared__ __attribute__((aligned(16))) unsigned short BsV[128 * 72];   // 18KB
  __shared__ float invsL[128];

  // XCD swizzle (NWG = 4*8*32 = 1024)
  int flat = blockIdx.x + 4 * (blockIdx.y + 8 * blockIdx.z);
  flat = (flat % 8) * 128 + flat / 8;
  const int bx = flat % 4;
  const int by = (flat / 4) % 8;
  const int bh = flat / 32;

  const int t = threadIdx.x;
  const int lane = t & 63, wave = t >> 6;
  const int wr = wave >> 1, wc = wave & 1;
  const int fr = lane & 15, fq = lane >> 4;
  const int m0 = by * 128, n0 = bx * 128;

  if (t < 128) {
    const float* pp = partials + ((size_t)bh * LQ + m0 + t) * 8;
    float s = ((pp[0] + pp[1]) + (pp[2] + pp[3])) + ((pp[4] + pp[5]) + (pp[6] + pp[7]));
    invsL[t] = 1.0f / s;
  }

  const char* Ab  = (const char*)P + ((size_t)bh * LQ + m0) * 2048;
  const float* Vb = V + (size_t)bh * LQ * DK + n0;

  f32x4 acc[4][4];
  #pragma unroll
  for (int i = 0; i < 4; ++i)
    #pragma unroll
    for (int j = 0; j < 4; ++j) acc[i][j] = (f32x4){0.f, 0.f, 0.f, 0.f};

  const int g  = t >> 5;   // 0..7 (k-group of 8)
  const int nl = t & 31;   // 0..31

  float vf[8][4];          // V prefetch registers (held across compute)
  auto V_LOAD = [&](int k0) {
    #pragma unroll
    for (int i = 0; i < 8; ++i) {
      const size_t rb = (size_t)(k0 + 8 * g + i) * DK;
      #pragma unroll
      for (int jn = 0; jn < 4; ++jn)
        vf[i][jn] = Vb[rb + nl + 32 * jn];
    }
  };
  auto V_STORE = [&]() {
    #pragma unroll
    for (int jn = 0; jn < 4; ++jn) {
      const int n = nl + 32 * jn;
      uint2 w0, w1;
      w0.x = pkbf(vf[0][jn], vf[1][jn]); w0.y = pkbf(vf[2][jn], vf[3][jn]);
      w1.x = pkbf(vf[4][jn], vf[5][jn]); w1.y = pkbf(vf[6][jn], vf[7][jn]);
      *(uint2*)((char*)BsV + n * 144 + 16 * g)     = w0;
      *(uint2*)((char*)BsV + n * 144 + 16 * g + 8) = w1;
    }
  };

  V_LOAD(0);   // prologue prefetch

  for (int k0 = 0; k0 < LQ; k0 += 64) {
    __syncthreads();               // all waves done reading As/BsV(prev)
    V_STORE();                     // regs completed by previous barrier drain
    #pragma unroll
    for (int i = 0; i < 4; ++i) {
      const int p  = i * 4096 + t * 16;
      const int r  = p >> 7;
      const int ch = (p >> 4) & 7;
      const int sw = ((ch ^ (r & 7)) << 4);
      lds_load16(Ab + (size_t)r * 2048 + k0 * 2 + sw, (char*)As + wave * 1024 + i * 4096);
    }
    if (k0 + 64 < LQ) V_LOAD(k0 + 64);
    __syncthreads();               // drains vmcnt: As ready, VSTORE visible

    #pragma unroll
    for (int kk = 0; kk < 2; ++kk) {
      short8 a[4], b[4];
      #pragma unroll
      for (int mi = 0; mi < 4; ++mi) {
        const int r  = wr * 64 + mi * 16 + fr;
        const int ch = (kk * 4 + fq) ^ (r & 7);
        a[mi] = *(const short8*)((const char*)As + r * 128 + ch * 16);
      }
      #pragma unroll
      for (int ni = 0; ni < 4; ++ni) {
        const int r = wc * 64 + ni * 16 + fr;
        b[ni] = *(const short8*)((const char*)BsV + r * 144 + (kk * 4 + fq) * 16);
      }
      #pragma unroll
      for (int mi = 0; mi < 4; ++mi)
        #pragma unroll
        for (int ni = 0; ni < 4; ++ni)
          acc[mi][ni] = __builtin_amdgcn_mfma_f32_16x16x32_bf16(a[mi], b[ni], acc[mi][ni], 0, 0, 0);
    }
  }

  const size_t obase = (size_t)bh * LQ * DK;
  #pragma unroll
  for (int mi = 0; mi < 4; ++mi)
    #pragma unroll
    for (int ni = 0; ni < 4; ++ni) {
      const int col = n0 + wc * 64 + ni * 16 + fr;
      #pragma unroll
      for (int r = 0; r < 4; ++r) {
        const int rloc = wr * 64 + mi * 16 + fq * 4 + r;
        O[obase + (size_t)(m0 + rloc) * DK + col] = acc[mi][ni][r] * invsL[rloc];
      }
    }
}

// ===========================================================================
// Fallback path (round-1 kernels, no workspace needed)
// ===========================================================================
__global__ __launch_bounds__(256) void qk_mask_kernel(
    const float* __restrict__ Q, const float* __restrict__ Kmat,
    const int* __restrict__ mask, float* __restrict__ S) {
  __shared__ __attribute__((aligned(16))) unsigned short Asf[128][40];
  __shared__ __attribute__((aligned(16))) unsigned short Bsf[128][40];
  const int t = threadIdx.x;
  const int lane = t & 63, wave = t >> 6;
  const int wr = wave >> 1, wc = wave & 1;
  const int fr = lane & 15, fq = lane >> 4;
  const int bh = blockIdx.z;
  const int m0 = blockIdx.y * 128, n0 = blockIdx.x * 128;
  const float* Qb = Q + (size_t)bh * LQ * DK;
  const float* Kb = Kmat + (size_t)bh * LQ * DK;
  unsigned int orv = 0;
  { const unsigned int* mw = (const unsigned int*)mask;
    #pragma unroll
    for (int i = 0; i < 64; ++i) orv |= mw[i]; }
  const bool byteMode = (orv > 1u);
  f32x4 acc[4][4];
  #pragma unroll
  for (int i = 0; i < 4; ++i)
    #pragma unroll
    for (int j = 0; j < 4; ++j) acc[i][j] = (f32x4){0.f,0.f,0.f,0.f};
  const int sr = t >> 1, sc = (t & 1) * 16;
  for (int kd = 0; kd < DK; kd += 32) {
    __syncthreads();
    { const float4* qa = (const float4*)(Qb + (size_t)(m0+sr)*DK + kd + sc);
      float fv[16];
      #pragma unroll
      for (int i = 0; i < 4; ++i) { float4 x = qa[i];
        fv[4*i]=x.x; fv[4*i+1]=x.y; fv[4*i+2]=x.z; fv[4*i+3]=x.w; }
      unsigned short us[16] __attribute__((aligned(16)));
      #pragma unroll
      for (int i = 0; i < 16; ++i) us[i] = cvt_bf16(fv[i]);
      *(short8*)&Asf[sr][sc]   = *(short8*)&us[0];
      *(short8*)&Asf[sr][sc+8] = *(short8*)&us[8]; }
    { const float4* ka = (const float4*)(Kb + (size_t)(n0+sr)*DK + kd + sc);
      float fv[16];
      #pragma unroll
      for (int i = 0; i < 4; ++i) { float4 x = ka[i];
        fv[4*i]=x.x; fv[4*i+1]=x.y; fv[4*i+2]=x.z; fv[4*i+3]=x.w; }
      unsigned short us[16] __attribute__((aligned(16)));
      #pragma unroll
      for (int i = 0; i < 16; ++i) us[i] = cvt_bf16(fv[i]);
      *(short8*)&Bsf[sr][sc]   = *(short8*)&us[0];
      *(short8*)&Bsf[sr][sc+8] = *(short8*)&us[8]; }
    __syncthreads();
    short8 a[4], b[4];
    #pragma unroll
    for (int mi = 0; mi < 4; ++mi) a[mi] = *(const short8*)&Asf[wr*64+mi*16+fr][fq*8];
    #pragma unroll
    for (int ni = 0; ni < 4; ++ni) b[ni] = *(const short8*)&Bsf[wc*64+ni*16+fr][fq*8];
    #pragma unroll
    for (int mi = 0; mi < 4; ++mi)
      #pragma unroll
      for (int ni = 0; ni < 4; ++ni)
        acc[mi][ni] = __builtin_amdgcn_mfma_f32_16x16x32_bf16(a[mi], b[ni], acc[mi][ni], 0, 0, 0);
  }
  const size_t sbase = (size_t)bh * LQ * LQ;
  const unsigned char* mb = (const unsigned char*)mask;
  #pragma unroll
  for (int mi = 0; mi < 4; ++mi)
    #pragma unroll
    for (int ni = 0; ni < 4; ++ni) {
      const int col = n0 + wc*64 + ni*16 + fr;
      #pragma unroll
      for (int r = 0; r < 4; ++r) {
        const int row = m0 + wr*64 + mi*16 + fq*4 + r;
        const size_t idx = sbase + (size_t)row * LQ + col;
        float s = acc[mi][ni][r] * SCALE;
        const bool msk = byteMode ? (mb[idx] != 0) : (mask[idx] != 0);
        S[idx] = msk ? -1e9f : s;
      }
    }
}

__global__ __launch_bounds__(256) void softmax_kernel(float* __restrict__ A) {
  const int row = blockIdx.x;
  float4* rp = (float4*)(A + (size_t)row * LQ);
  const int t = threadIdx.x;
  float4 v = rp[t];
  float m = fmaxf(fmaxf(v.x, v.y), fmaxf(v.z, v.w));
  #pragma unroll
  for (int off = 32; off >= 1; off >>= 1) m = fmaxf(m, __shfl_xor(m, off, 64));
  __shared__ float redm[4];
  const int wv = t >> 6, ln = t & 63;
  if (ln == 0) redm[wv] = m;
  __syncthreads();
  m = fmaxf(fmaxf(redm[0], redm[1]), fmaxf(redm[2], redm[3]));
  float4 e;
  e.x = expf(v.x - m); e.y = expf(v.y - m); e.z = expf(v.z - m); e.w = expf(v.w - m);
  float s = (e.x + e.y) + (e.z + e.w);
  #pragma unroll
  for (int off = 32; off >= 1; off >>= 1) s += __shfl_xor(s, off, 64);
  __shared__ float reds2[4];
  if (ln == 0) reds2[wv] = s;
  __syncthreads();
  s = (reds2[0] + reds2[1]) + (reds2[2] + reds2[3]);
  const float inv = 1.0f / s;
  e.x *= inv; e.y *= inv; e.z *= inv; e.w *= inv;
  rp[t] = e;
}

__global__ __launch_bounds__(256) void pv_kernel(
    const float* __restrict__ P, const float* __restrict__ V, float* __restrict__ O) {
  __shared__ __attribute__((aligned(16))) unsigned short Ps[128][40];
  __shared__ __attribute__((aligned(16))) unsigned short Vtl[128][40];
  const int t = threadIdx.x;
  const int lane = t & 63, wave = t >> 6;
  const int wr = wave >> 1, wc = wave & 1;
  const int fr = lane & 15, fq = lane >> 4;
  const int bh = blockIdx.z;
  const int m0 = blockIdx.y * 128, n0 = blockIdx.x * 128;
  const float* Pb = P + (size_t)bh * LQ * LQ;
  const float* Vb = V + (size_t)bh * LQ * DK;
  f32x4 acc[4][4];
  #pragma unroll
  for (int i = 0; i < 4; ++i)
    #pragma unroll
    for (int j = 0; j < 4; ++j) acc[i][j] = (f32x4){0.f,0.f,0.f,0.f};
  const int sr = t >> 1, sc = (t & 1) * 16;
  const int kk = (t & 15) * 2, nn = (t >> 4) * 8;
  for (int k0 = 0; k0 < LQ; k0 += 32) {
    __syncthreads();
    { const float4* pa = (const float4*)(Pb + (size_t)(m0+sr)*LQ + k0 + sc);
      float fv[16];
      #pragma unroll
      for (int i = 0; i < 4; ++i) { float4 x = pa[i];
        fv[4*i]=x.x; fv[4*i+1]=x.y; fv[4*i+2]=x.z; fv[4*i+3]=x.w; }
      unsigned short us[16] __attribute__((aligned(16)));
      #pragma unroll
      for (int i = 0; i < 16; ++i) us[i] = cvt_bf16(fv[i]);
      *(short8*)&Ps[sr][sc]   = *(short8*)&us[0];
      *(short8*)&Ps[sr][sc+8] = *(short8*)&us[8]; }
    { const float* v0p = Vb + (size_t)(k0+kk)*DK + n0 + nn;
      const float* v1p = v0p + DK;
      float4 a0 = *(const float4*)v0p, a1 = *(const float4*)(v0p+4);
      float4 b0 = *(const float4*)v1p, b1 = *(const float4*)(v1p+4);
      float r0[8] = {a0.x,a0.y,a0.z,a0.w,a1.x,a1.y,a1.z,a1.w};
      float r1[8] = {b0.x,b0.y,b0.z,b0.w,b1.x,b1.y,b1.z,b1.w};
      #pragma unroll
      for (int i = 0; i < 8; ++i) {
        unsigned int pk = (unsigned int)cvt_bf16(r0[i]) | ((unsigned int)cvt_bf16(r1[i]) << 16);
        *(unsigned int*)&Vtl[nn+i][kk] = pk; } }
    __syncthreads();
    short8 a[4], b[4];
    #pragma unroll
    for (int mi = 0; mi < 4; ++mi) a[mi] = *(const short8*)&Ps[wr*64+mi*16+fr][fq*8];
    #pragma unroll
    for (int ni = 0; ni < 4; ++ni) b[ni] = *(const short8*)&Vtl[wc*64+ni*16+fr][fq*8];
    #pragma unroll
    for (int mi = 0; mi < 4; ++mi)
      #pragma unroll
      for (int ni = 0; ni < 4; ++ni)
        acc[mi][ni] = __builtin_amdgcn_mfma_f32_16x16x32_bf16(a[mi], b[ni], acc[mi][ni], 0, 0, 0);
  }
  const size_t obase = (size_t)bh * LQ * DK;
  #pragma unroll
  for (int mi = 0; mi < 4; ++mi)
    #pragma unroll
    for (int ni = 0; ni < 4; ++ni) {
      const int col = n0 + wc*64 + ni*16 + fr;
      #pragma unroll
      for (int r = 0; r < 4; ++r) {
        const int row = m0 + wr*64 + mi*16 + fq*4 + r;
        O[obase + (size_t)row * DK + col] = acc[mi][ni][r];
      }
    }
}

// ---------------------------------------------------------------------------
extern "C" void kernel_launch(void* const* d_in, const int* in_sizes, int n_in,
                              void* d_out, int out_size, void* d_ws, size_t ws_size,
                              hipStream_t stream) {
  const float* Q    = (const float*)d_in[0];
  const float* K    = (const float*)d_in[1];
  const float* V    = (const float*)d_in[2];
  const int*   mask = (const int*)d_in[3];

  float* ctx  = (float*)d_out;                  // [32,1024,512] fp32 (67.1MB)
  float* attn = ctx + (size_t)BH * LQ * DK;     // [32,1024,1024] fp32 (134MB)

  const size_t P_BYTES  = (size_t)BH * LQ * LQ * 2;           // 67.1MB bf16
  const size_t WS_NEED  = P_BYTES + (size_t)BH * LQ * 8 * 4;  // + partials 1MB

  if (ws_size >= WS_NEED) {
    unsigned short* Pp       = (unsigned short*)d_ws;
    float*          partials = (float*)((char*)d_ws + P_BYTES);

    qk_v6_kernel<<<dim3(8, 4, BH), 512, 0, stream>>>(Q, K, mask, Pp, partials);
    attn_fin<<<dim3(2, 16, BH), 256, 0, stream>>>(Pp, partials, attn);
    pv2_kernel<<<dim3(4, 8, BH), 256, 0, stream>>>(Pp, V, partials, ctx);
  } else {
    qk_mask_kernel<<<dim3(8, 8, BH), 256, 0, stream>>>(Q, K, mask, attn);
    softmax_kernel<<<dim3(BH * LQ), 256, 0, stream>>>(attn);
    pv_kernel<<<dim3(4, 8, BH), 256, 0, stream>>>(attn, V, ctx);
  }
}

// Round 14
// 222.076 us; speedup vs baseline: 1.0203x; 1.0203x over previous
//
#include <hip/hip_runtime.h>
#include <hip/hip_bf16.h>

constexpr int BH  = 32;     // B*H
constexpr int LQ  = 1024;
constexpr int DK  = 512;
constexpr float SCALE = 0.04419417382415922f;  // 1/sqrt(512)

using short8 = __attribute__((ext_vector_type(8))) short;
using f32x4  = __attribute__((ext_vector_type(4))) float;

__device__ __forceinline__ unsigned short cvt_bf16(float x) {
  unsigned int u = __builtin_bit_cast(unsigned int, x);
  u += 0x7FFFu + ((u >> 16) & 1u);   // RNE
  return (unsigned short)(u >> 16);
}
__device__ __forceinline__ float bf2f(unsigned short s) {
  return __builtin_bit_cast(float, (unsigned int)s << 16);
}
// HW packed fp32->bf16 (RNE), non-volatile (schedulable).
__device__ __forceinline__ unsigned int pkbf(float lo, float hi) {
  unsigned int r;
  asm("v_cvt_pk_bf16_f32 %0, %1, %2" : "=v"(r) : "v"(lo), "v"(hi));
  return r;
}

// async global->LDS, 16B per lane. LDS dest must be wave-uniform (HW adds lane*16).
__device__ __forceinline__ void lds_load16(const void* g, void* l) {
  __builtin_amdgcn_global_load_lds(
      (const __attribute__((address_space(1))) unsigned int*)g,
      (__attribute__((address_space(3))) unsigned int*)l, 16, 0, 0);
}

// ---------------------------------------------------------------------------
// cvt2: fp32 -> bf16 for Q and K in one launch (blockIdx.y picks tensor)
// ---------------------------------------------------------------------------
__global__ __launch_bounds__(256) void cvt2_f32_bf16(
    const float* __restrict__ s0, const float* __restrict__ s1,
    unsigned short* __restrict__ d0, unsigned short* __restrict__ d1, int n8) {
  const float* src = blockIdx.y ? s1 : s0;
  unsigned short* dst = blockIdx.y ? d1 : d0;
  int i = blockIdx.x * 256 + threadIdx.x;
  const int stride = gridDim.x * 256;
  for (; i < n8; i += stride) {
    float4 a = ((const float4*)src)[(size_t)i * 2];
    float4 b = ((const float4*)src)[(size_t)i * 2 + 1];
    unsigned int w[4] __attribute__((aligned(16)));
    w[0] = pkbf(a.x, a.y); w[1] = pkbf(a.z, a.w);
    w[2] = pkbf(b.x, b.y); w[3] = pkbf(b.z, b.w);
    ((uint4*)dst)[i] = *(uint4*)w;
  }
}

// ---------------------------------------------------------------------------
// qk_v7: P' = exp(scale*Q.K^T) masked->0 (bf16) + per-row partial sums.
// Combines the two measured qk levers: 3 blocks/CU occupancy (48KB LDS) AND
// double-buffered global_load_lds prefetch. Tile 256(M) x 128(N), BK=32,
// 16 k-iters, 8 waves (4M x 2N), grid 1024 blocks. 2 x (A 16KB + B 8KB).
// Swizzle: chunk ^= (r&3) on 64B rows, same on gload source and ds_read.
// ---------------------------------------------------------------------------
__global__ __launch_bounds__(512) void qk_v7_kernel(
    const unsigned short* __restrict__ A, const unsigned short* __restrict__ B,
    const int* __restrict__ mask, unsigned short* __restrict__ P,
    float* __restrict__ partials) {
  __shared__ __attribute__((aligned(16))) unsigned short smem[24576];  // 49152 B

  // XCD-aware bijective swizzle (NWG = 8*4*32 = 1024, %8==0)
  int flat = blockIdx.x + 8 * (blockIdx.y + 4 * blockIdx.z);
  flat = (flat % 8) * 128 + flat / 8;
  const int bx = flat % 8;            // N tile (128 cols)
  const int by = (flat / 8) % 4;      // M tile (256 rows)
  const int bh = flat / 32;

  const int t = threadIdx.x;          // 0..511
  const int lane = t & 63, wave = t >> 6;
  const int wr = wave >> 1;           // 0..3 (64-row band)
  const int wc = wave & 1;            // 0..1 (64-col band)
  const int fr = lane & 15, fq = lane >> 4;
  const int m0 = by * 256, n0 = bx * 128;

  const char* Ab = (const char*)A + ((size_t)bh * LQ + m0) * 1024;
  const char* Bb = (const char*)B + ((size_t)bh * LQ + n0) * 1024;

  // mask dtype detection (uniform)
  unsigned int orv = 0;
  {
    const unsigned int* mw = (const unsigned int*)mask;
    #pragma unroll
    for (int i = 0; i < 64; ++i) orv |= mw[i];
  }
  const bool byteMode = (orv > 1u);

  f32x4 acc[4][4];
  #pragma unroll
  for (int i = 0; i < 4; ++i)
    #pragma unroll
    for (int j = 0; j < 4; ++j) acc[i][j] = (f32x4){0.f, 0.f, 0.f, 0.f};

  // buf s: A at s*24576 (16KB: 256 rows x 64B), B at s*24576+16384 (8KB)
  auto STAGE = [&](int kt, int buf) {
    char* base = (char*)smem + buf * 24576;
    const int kb = kt * 64;           // byte offset of 32-col bf16 window
    #pragma unroll
    for (int i = 0; i < 2; ++i) {
      const int p  = i * 8192 + t * 16;
      const int r  = p >> 6;                 // A row 0..255 (64B rows)
      const int ch = (p >> 4) & 3;
      lds_load16(Ab + (size_t)r * 1024 + kb + ((ch ^ (r & 3)) << 4),
                 base + i * 8192 + wave * 1024);
    }
    {
      const int p  = t * 16;
      const int r  = p >> 6;                 // B row 0..127
      const int ch = (p >> 4) & 3;
      lds_load16(Bb + (size_t)r * 1024 + kb + ((ch ^ (r & 3)) << 4),
                 base + 16384 + wave * 1024);
    }
  };
  auto COMPUTE = [&](int buf) {
    const char* As = (const char*)smem + buf * 24576;
    const char* Bs = As + 16384;
    short8 a[4], b[4];
    #pragma unroll
    for (int mi = 0; mi < 4; ++mi) {
      const int r  = wr * 64 + mi * 16 + fr;          // 0..255
      const int ch = fq ^ (r & 3);
      a[mi] = *(const short8*)(As + r * 64 + ch * 16);
    }
    #pragma unroll
    for (int ni = 0; ni < 4; ++ni) {
      const int r  = wc * 64 + ni * 16 + fr;          // 0..127
      const int ch = fq ^ (r & 3);
      b[ni] = *(const short8*)(Bs + r * 64 + ch * 16);
    }
    #pragma unroll
    for (int mi = 0; mi < 4; ++mi)
      #pragma unroll
      for (int ni = 0; ni < 4; ++ni)
        acc[mi][ni] = __builtin_amdgcn_mfma_f32_16x16x32_bf16(a[mi], b[ni], acc[mi][ni], 0, 0, 0);
  };

  STAGE(0, 0);
  __syncthreads();                    // drains vmcnt: tile 0 ready
  int cur = 0;
  for (int kt = 0; kt < 16; ++kt) {
    if (kt < 15) STAGE(kt + 1, cur ^ 1);   // prefetch in flight over compute
    COMPUTE(cur);
    __syncthreads();                  // drains prefetch + all waves done w/ cur
    cur ^= 1;
  }

  // ---- epilogue in two 128-row halves (C-stage aliases staging LDS) ----
  unsigned short* Cs = smem;   // [128][136] bf16 = 34816 B
  const size_t pbase = (size_t)bh * LQ * LQ;
  #pragma unroll
  for (int h = 0; h < 2; ++h) {
    __syncthreads();
    if ((wr >> 1) == h) {
      #pragma unroll
      for (int mi = 0; mi < 4; ++mi)
        #pragma unroll
        for (int ni = 0; ni < 4; ++ni) {
          const int col = wc * 64 + ni * 16 + fr;
          #pragma unroll
          for (int r = 0; r < 4; ++r) {
            const int rloc = (wr & 1) * 64 + mi * 16 + fq * 4 + r;
            Cs[rloc * 136 + col] = cvt_bf16(__expf(acc[mi][ni][r] * SCALE));
          }
        }
    }
    __syncthreads();
    const int rl = t >> 4;          // 0..31
    const int cl = (t & 15) * 8;    // 0..120
    #pragma unroll
    for (int rb = 0; rb < 4; ++rb) {
      const int rloc = rb * 32 + rl;
      const int rg   = m0 + h * 128 + rloc;
      const size_t gidx = pbase + (size_t)rg * LQ + (n0 + cl);
      short8 sv = *(const short8*)&Cs[rloc * 136 + cl];
      bool mk[8];
      if (byteMode) {
        const unsigned char* mb = (const unsigned char*)mask + gidx;
        uint2 w = *(const uint2*)mb;
        #pragma unroll
        for (int j = 0; j < 4; ++j) mk[j]     = ((w.x >> (8 * j)) & 255u) != 0u;
        #pragma unroll
        for (int j = 0; j < 4; ++j) mk[4 + j] = ((w.y >> (8 * j)) & 255u) != 0u;
      } else {
        int4 w0 = *(const int4*)(mask + gidx);
        int4 w1 = *(const int4*)(mask + gidx + 4);
        mk[0] = w0.x != 0; mk[1] = w0.y != 0; mk[2] = w0.z != 0; mk[3] = w0.w != 0;
        mk[4] = w1.x != 0; mk[5] = w1.y != 0; mk[6] = w1.z != 0; mk[7] = w1.w != 0;
      }
      unsigned short out[8] __attribute__((aligned(16)));
      float s = 0.f;
      #pragma unroll
      for (int j = 0; j < 8; ++j) {
        unsigned short v = mk[j] ? (unsigned short)0 : (unsigned short)sv[j];
        out[j] = v;
        s += bf2f(v);
      }
      *(short8*)(P + gidx) = *(short8*)out;
      s += __shfl_xor(s, 1); s += __shfl_xor(s, 2);
      s += __shfl_xor(s, 4); s += __shfl_xor(s, 8);
      if ((t & 15) == 0)
        partials[((size_t)bh * LQ + rg) * 8 + bx] = s;
    }
  }
}

// ---------------------------------------------------------------------------
// attn_fin: attn[row][col] = P'[row][col] * (1/rowsum)  (bf16 -> fp32)
// ---------------------------------------------------------------------------
__global__ __launch_bounds__(256) void attn_fin(
    const unsigned short* __restrict__ P, const float* __restrict__ partials,
    float* __restrict__ attn) {
  const int ch = blockIdx.x, rb64 = blockIdx.y, bh = blockIdx.z;
  const int m0 = rb64 * 64;
  __shared__ float invs[64];
  const int t = threadIdx.x;
  if (t < 64) {
    const float* pp = partials + ((size_t)bh * LQ + m0 + t) * 8;
    float s = ((pp[0] + pp[1]) + (pp[2] + pp[3])) + ((pp[4] + pp[5]) + (pp[6] + pp[7]));
    invs[t] = 1.0f / s;
  }
  __syncthreads();
  const size_t pbase = (size_t)bh * LQ * LQ;
  const int c0 = ch * 512;
  #pragma unroll
  for (int rb = 0; rb < 4; ++rb) {
    const int rloc = rb * 16 + (t >> 4);
    const int row  = m0 + rloc;
    const float inv = invs[rloc];
    const size_t base = pbase + (size_t)row * LQ + c0 + (t & 15) * 8;
    #pragma unroll
    for (int j = 0; j < 4; ++j) {
      short8 sv = *(const short8*)(P + base + j * 128);
      float4 o0, o1;
      o0.x = bf2f((unsigned short)sv[0]) * inv;
      o0.y = bf2f((unsigned short)sv[1]) * inv;
      o0.z = bf2f((unsigned short)sv[2]) * inv;
      o0.w = bf2f((unsigned short)sv[3]) * inv;
      o1.x = bf2f((unsigned short)sv[4]) * inv;
      o1.y = bf2f((unsigned short)sv[5]) * inv;
      o1.z = bf2f((unsigned short)sv[6]) * inv;
      o1.w = bf2f((unsigned short)sv[7]) * inv;
      *(float4*)(attn + base + j * 128)     = o0;
      *(float4*)(attn + base + j * 128 + 4) = o1;
    }
  }
}

// ---------------------------------------------------------------------------
// pv2: ctx = (P' . V) * invrow.  Single LDS buffer + T14 split (round-12
// proven): V loads for k+1 issued before the barrier; pack+write after it.
// ---------------------------------------------------------------------------
__global__ __launch_bounds__(256) void pv2_kernel(
    const unsigned short* __restrict__ P, const float* __restrict__ V,
    const float* __restrict__ partials, float* __restrict__ O) {
  __shared__ __attribute__((aligned(16))) unsigned short As[8192];        // 16KB
  __shared__ __attribute__((aligned(16))) unsigned short BsV[128 * 72];   // 18KB
  __shared__ float invsL[128];

  // XCD swizzle (NWG = 4*8*32 = 1024)
  int flat = blockIdx.x + 4 * (blockIdx.y + 8 * blockIdx.z);
  flat = (flat % 8) * 128 + flat / 8;
  const int bx = flat % 4;
  const int by = (flat / 4) % 8;
  const int bh = flat / 32;

  const int t = threadIdx.x;
  const int lane = t & 63, wave = t >> 6;
  const int wr = wave >> 1, wc = wave & 1;
  const int fr = lane & 15, fq = lane >> 4;
  const int m0 = by * 128, n0 = bx * 128;

  if (t < 128) {
    const float* pp = partials + ((size_t)bh * LQ + m0 + t) * 8;
    float s = ((pp[0] + pp[1]) + (pp[2] + pp[3])) + ((pp[4] + pp[5]) + (pp[6] + pp[7]));
    invsL[t] = 1.0f / s;
  }

  const char* Ab  = (const char*)P + ((size_t)bh * LQ + m0) * 2048;
  const float* Vb = V + (size_t)bh * LQ * DK + n0;

  f32x4 acc[4][4];
  #pragma unroll
  for (int i = 0; i < 4; ++i)
    #pragma unroll
    for (int j = 0; j < 4; ++j) acc[i][j] = (f32x4){0.f, 0.f, 0.f, 0.f};

  const int g  = t >> 5;   // 0..7 (k-group of 8)
  const int nl = t & 31;   // 0..31

  float vf[8][4];          // V prefetch registers (held across compute)
  auto V_LOAD = [&](int k0) {
    #pragma unroll
    for (int i = 0; i < 8; ++i) {
      const size_t rb = (size_t)(k0 + 8 * g + i) * DK;
      #pragma unroll
      for (int jn = 0; jn < 4; ++jn)
        vf[i][jn] = Vb[rb + nl + 32 * jn];
    }
  };
  auto V_STORE = [&]() {
    #pragma unroll
    for (int jn = 0; jn < 4; ++jn) {
      const int n = nl + 32 * jn;
      uint2 w0, w1;
      w0.x = pkbf(vf[0][jn], vf[1][jn]); w0.y = pkbf(vf[2][jn], vf[3][jn]);
      w1.x = pkbf(vf[4][jn], vf[5][jn]); w1.y = pkbf(vf[6][jn], vf[7][jn]);
      *(uint2*)((char*)BsV + n * 144 + 16 * g)     = w0;
      *(uint2*)((char*)BsV + n * 144 + 16 * g + 8) = w1;
    }
  };

  V_LOAD(0);   // prologue prefetch

  for (int k0 = 0; k0 < LQ; k0 += 64) {
    __syncthreads();               // all waves done reading As/BsV(prev)
    V_STORE();                     // regs completed by previous barrier drain
    #pragma unroll
    for (int i = 0; i < 4; ++i) {
      const int p  = i * 4096 + t * 16;
      const int r  = p >> 7;
      const int ch = (p >> 4) & 7;
      const int sw = ((ch ^ (r & 7)) << 4);
      lds_load16(Ab + (size_t)r * 2048 + k0 * 2 + sw, (char*)As + wave * 1024 + i * 4096);
    }
    if (k0 + 64 < LQ) V_LOAD(k0 + 64);
    __syncthreads();               // drains vmcnt: As ready, VSTORE visible

    #pragma unroll
    for (int kk = 0; kk < 2; ++kk) {
      short8 a[4], b[4];
      #pragma unroll
      for (int mi = 0; mi < 4; ++mi) {
        const int r  = wr * 64 + mi * 16 + fr;
        const int ch = (kk * 4 + fq) ^ (r & 7);
        a[mi] = *(const short8*)((const char*)As + r * 128 + ch * 16);
      }
      #pragma unroll
      for (int ni = 0; ni < 4; ++ni) {
        const int r = wc * 64 + ni * 16 + fr;
        b[ni] = *(const short8*)((const char*)BsV + r * 144 + (kk * 4 + fq) * 16);
      }
      #pragma unroll
      for (int mi = 0; mi < 4; ++mi)
        #pragma unroll
        for (int ni = 0; ni < 4; ++ni)
          acc[mi][ni] = __builtin_amdgcn_mfma_f32_16x16x32_bf16(a[mi], b[ni], acc[mi][ni], 0, 0, 0);
    }
  }

  const size_t obase = (size_t)bh * LQ * DK;
  #pragma unroll
  for (int mi = 0; mi < 4; ++mi)
    #pragma unroll
    for (int ni = 0; ni < 4; ++ni) {
      const int col = n0 + wc * 64 + ni * 16 + fr;
      #pragma unroll
      for (int r = 0; r < 4; ++r) {
        const int rloc = wr * 64 + mi * 16 + fq * 4 + r;
        O[obase + (size_t)(m0 + rloc) * DK + col] = acc[mi][ni][r] * invsL[rloc];
      }
    }
}

// ===========================================================================
// Fallback path (round-1 kernels, no workspace needed)
// ===========================================================================
__global__ __launch_bounds__(256) void qk_mask_kernel(
    const float* __restrict__ Q, const float* __restrict__ Kmat,
    const int* __restrict__ mask, float* __restrict__ S) {
  __shared__ __attribute__((aligned(16))) unsigned short Asf[128][40];
  __shared__ __attribute__((aligned(16))) unsigned short Bsf[128][40];
  const int t = threadIdx.x;
  const int lane = t & 63, wave = t >> 6;
  const int wr = wave >> 1, wc = wave & 1;
  const int fr = lane & 15, fq = lane >> 4;
  const int bh = blockIdx.z;
  const int m0 = blockIdx.y * 128, n0 = blockIdx.x * 128;
  const float* Qb = Q + (size_t)bh * LQ * DK;
  const float* Kb = Kmat + (size_t)bh * LQ * DK;
  unsigned int orv = 0;
  { const unsigned int* mw = (const unsigned int*)mask;
    #pragma unroll
    for (int i = 0; i < 64; ++i) orv |= mw[i]; }
  const bool byteMode = (orv > 1u);
  f32x4 acc[4][4];
  #pragma unroll
  for (int i = 0; i < 4; ++i)
    #pragma unroll
    for (int j = 0; j < 4; ++j) acc[i][j] = (f32x4){0.f,0.f,0.f,0.f};
  const int sr = t >> 1, sc = (t & 1) * 16;
  for (int kd = 0; kd < DK; kd += 32) {
    __syncthreads();
    { const float4* qa = (const float4*)(Qb + (size_t)(m0+sr)*DK + kd + sc);
      float fv[16];
      #pragma unroll
      for (int i = 0; i < 4; ++i) { float4 x = qa[i];
        fv[4*i]=x.x; fv[4*i+1]=x.y; fv[4*i+2]=x.z; fv[4*i+3]=x.w; }
      unsigned short us[16] __attribute__((aligned(16)));
      #pragma unroll
      for (int i = 0; i < 16; ++i) us[i] = cvt_bf16(fv[i]);
      *(short8*)&Asf[sr][sc]   = *(short8*)&us[0];
      *(short8*)&Asf[sr][sc+8] = *(short8*)&us[8]; }
    { const float4* ka = (const float4*)(Kb + (size_t)(n0+sr)*DK + kd + sc);
      float fv[16];
      #pragma unroll
      for (int i = 0; i < 4; ++i) { float4 x = ka[i];
        fv[4*i]=x.x; fv[4*i+1]=x.y; fv[4*i+2]=x.z; fv[4*i+3]=x.w; }
      unsigned short us[16] __attribute__((aligned(16)));
      #pragma unroll
      for (int i = 0; i < 16; ++i) us[i] = cvt_bf16(fv[i]);
      *(short8*)&Bsf[sr][sc]   = *(short8*)&us[0];
      *(short8*)&Bsf[sr][sc+8] = *(short8*)&us[8]; }
    __syncthreads();
    short8 a[4], b[4];
    #pragma unroll
    for (int mi = 0; mi < 4; ++mi) a[mi] = *(const short8*)&Asf[wr*64+mi*16+fr][fq*8];
    #pragma unroll
    for (int ni = 0; ni < 4; ++ni) b[ni] = *(const short8*)&Bsf[wc*64+ni*16+fr][fq*8];
    #pragma unroll
    for (int mi = 0; mi < 4; ++mi)
      #pragma unroll
      for (int ni = 0; ni < 4; ++ni)
        acc[mi][ni] = __builtin_amdgcn_mfma_f32_16x16x32_bf16(a[mi], b[ni], acc[mi][ni], 0, 0, 0);
  }
  const size_t sbase = (size_t)bh * LQ * LQ;
  const unsigned char* mb = (const unsigned char*)mask;
  #pragma unroll
  for (int mi = 0; mi < 4; ++mi)
    #pragma unroll
    for (int ni = 0; ni < 4; ++ni) {
      const int col = n0 + wc*64 + ni*16 + fr;
      #pragma unroll
      for (int r = 0; r < 4; ++r) {
        const int row = m0 + wr*64 + mi*16 + fq*4 + r;
        const size_t idx = sbase + (size_t)row * LQ + col;
        float s = acc[mi][ni][r] * SCALE;
        const bool msk = byteMode ? (mb[idx] != 0) : (mask[idx] != 0);
        S[idx] = msk ? -1e9f : s;
      }
    }
}

__global__ __launch_bounds__(256) void softmax_kernel(float* __restrict__ A) {
  const int row = blockIdx.x;
  float4* rp = (float4*)(A + (size_t)row * LQ);
  const int t = threadIdx.x;
  float4 v = rp[t];
  float m = fmaxf(fmaxf(v.x, v.y), fmaxf(v.z, v.w));
  #pragma unroll
  for (int off = 32; off >= 1; off >>= 1) m = fmaxf(m, __shfl_xor(m, off, 64));
  __shared__ float redm[4];
  const int wv = t >> 6, ln = t & 63;
  if (ln == 0) redm[wv] = m;
  __syncthreads();
  m = fmaxf(fmaxf(redm[0], redm[1]), fmaxf(redm[2], redm[3]));
  float4 e;
  e.x = expf(v.x - m); e.y = expf(v.y - m); e.z = expf(v.z - m); e.w = expf(v.w - m);
  float s = (e.x + e.y) + (e.z + e.w);
  #pragma unroll
  for (int off = 32; off >= 1; off >>= 1) s += __shfl_xor(s, off, 64);
  __shared__ float reds2[4];
  if (ln == 0) reds2[wv] = s;
  __syncthreads();
  s = (reds2[0] + reds2[1]) + (reds2[2] + reds2[3]);
  const float inv = 1.0f / s;
  e.x *= inv; e.y *= inv; e.z *= inv; e.w *= inv;
  rp[t] = e;
}

__global__ __launch_bounds__(256) void pv_kernel(
    const float* __restrict__ P, const float* __restrict__ V, float* __restrict__ O) {
  __shared__ __attribute__((aligned(16))) unsigned short Ps[128][40];
  __shared__ __attribute__((aligned(16))) unsigned short Vtl[128][40];
  const int t = threadIdx.x;
  const int lane = t & 63, wave = t >> 6;
  const int wr = wave >> 1, wc = wave & 1;
  const int fr = lane & 15, fq = lane >> 4;
  const int bh = blockIdx.z;
  const int m0 = blockIdx.y * 128, n0 = blockIdx.x * 128;
  const float* Pb = P + (size_t)bh * LQ * LQ;
  const float* Vb = V + (size_t)bh * LQ * DK;
  f32x4 acc[4][4];
  #pragma unroll
  for (int i = 0; i < 4; ++i)
    #pragma unroll
    for (int j = 0; j < 4; ++j) acc[i][j] = (f32x4){0.f,0.f,0.f,0.f};
  const int sr = t >> 1, sc = (t & 1) * 16;
  const int kk = (t & 15) * 2, nn = (t >> 4) * 8;
  for (int k0 = 0; k0 < LQ; k0 += 32) {
    __syncthreads();
    { const float4* pa = (const float4*)(Pb + (size_t)(m0+sr)*LQ + k0 + sc);
      float fv[16];
      #pragma unroll
      for (int i = 0; i < 4; ++i) { float4 x = pa[i];
        fv[4*i]=x.x; fv[4*i+1]=x.y; fv[4*i+2]=x.z; fv[4*i+3]=x.w; }
      unsigned short us[16] __attribute__((aligned(16)));
      #pragma unroll
      for (int i = 0; i < 16; ++i) us[i] = cvt_bf16(fv[i]);
      *(short8*)&Ps[sr][sc]   = *(short8*)&us[0];
      *(short8*)&Ps[sr][sc+8] = *(short8*)&us[8]; }
    { const float* v0p = Vb + (size_t)(k0+kk)*DK + n0 + nn;
      const float* v1p = v0p + DK;
      float4 a0 = *(const float4*)v0p, a1 = *(const float4*)(v0p+4);
      float4 b0 = *(const float4*)v1p, b1 = *(const float4*)(v1p+4);
      float r0[8] = {a0.x,a0.y,a0.z,a0.w,a1.x,a1.y,a1.z,a1.w};
      float r1[8] = {b0.x,b0.y,b0.z,b0.w,b1.x,b1.y,b1.z,b1.w};
      #pragma unroll
      for (int i = 0; i < 8; ++i) {
        unsigned int pk = (unsigned int)cvt_bf16(r0[i]) | ((unsigned int)cvt_bf16(r1[i]) << 16);
        *(unsigned int*)&Vtl[nn+i][kk] = pk; } }
    __syncthreads();
    short8 a[4], b[4];
    #pragma unroll
    for (int mi = 0; mi < 4; ++mi) a[mi] = *(const short8*)&Ps[wr*64+mi*16+fr][fq*8];
    #pragma unroll
    for (int ni = 0; ni < 4; ++ni) b[ni] = *(const short8*)&Vtl[wc*64+ni*16+fr][fq*8];
    #pragma unroll
    for (int mi = 0; mi < 4; ++mi)
      #pragma unroll
      for (int ni = 0; ni < 4; ++ni)
        acc[mi][ni] = __builtin_amdgcn_mfma_f32_16x16x32_bf16(a[mi], b[ni], acc[mi][ni], 0, 0, 0);
  }
  const size_t obase = (size_t)bh * LQ * DK;
  #pragma unroll
  for (int mi = 0; mi < 4; ++mi)
    #pragma unroll
    for (int ni = 0; ni < 4; ++ni) {
      const int col = n0 + wc*64 + ni*16 + fr;
      #pragma unroll
      for (int r = 0; r < 4; ++r) {
        const int row = m0 + wr*64 + mi*16 + fq*4 + r;
        O[obase + (size_t)row * DK + col] = acc[mi][ni][r];
      }
    }
}

// ---------------------------------------------------------------------------
extern "C" void kernel_launch(void* const* d_in, const int* in_sizes, int n_in,
                              void* d_out, int out_size, void* d_ws, size_t ws_size,
                              hipStream_t stream) {
  const float* Q    = (const float*)d_in[0];
  const float* K    = (const float*)d_in[1];
  const float* V    = (const float*)d_in[2];
  const int*   mask = (const int*)d_in[3];

  float* ctx  = (float*)d_out;                  // [32,1024,512] fp32 (67.1MB)
  float* attn = ctx + (size_t)BH * LQ * DK;     // [32,1024,1024] fp32 (134MB)

  const size_t NE = (size_t)BH * LQ * DK;       // 16.78M elems
  const size_t P_BYTES  = (size_t)BH * LQ * LQ * 2;           // 67.1MB bf16
  const size_t WS_NEED  = P_BYTES + (size_t)BH * LQ * 8 * 4;  // + partials 1MB

  if (ws_size >= WS_NEED) {
    unsigned short* Pp       = (unsigned short*)d_ws;
    float*          partials = (float*)((char*)d_ws + P_BYTES);
    // Q,K bf16 live in the (dead until pv2) ctx output region
    unsigned short* Qb = (unsigned short*)ctx;
    unsigned short* Kb = Qb + NE;

    cvt2_f32_bf16<<<dim3(1024, 2), 256, 0, stream>>>(Q, K, Qb, Kb, (int)(NE / 8));
    qk_v7_kernel<<<dim3(8, 4, BH), 512, 0, stream>>>(Qb, Kb, mask, Pp, partials);
    attn_fin<<<dim3(2, 16, BH), 256, 0, stream>>>(Pp, partials, attn);
    pv2_kernel<<<dim3(4, 8, BH), 256, 0, stream>>>(Pp, V, partials, ctx);
  } else {
    qk_mask_kernel<<<dim3(8, 8, BH), 256, 0, stream>>>(Q, K, mask, attn);
    softmax_kernel<<<dim3(BH * LQ), 256, 0, stream>>>(attn);
    pv_kernel<<<dim3(4, 8, BH), 256, 0, stream>>>(attn, V, ctx);
  }
}

// Round 15
// 217.938 us; speedup vs baseline: 1.0397x; 1.0190x over previous
//
#include <hip/hip_runtime.h>
#include <hip/hip_bf16.h>

constexpr int BH  = 32;     // B*H
constexpr int LQ  = 1024;
constexpr int DK  = 512;
constexpr float SCALE = 0.04419417382415922f;  // 1/sqrt(512)

using short8 = __attribute__((ext_vector_type(8))) short;
using f32x4  = __attribute__((ext_vector_type(4))) float;

__device__ __forceinline__ unsigned short cvt_bf16(float x) {
  unsigned int u = __builtin_bit_cast(unsigned int, x);
  u += 0x7FFFu + ((u >> 16) & 1u);   // RNE
  return (unsigned short)(u >> 16);
}
__device__ __forceinline__ float bf2f(unsigned short s) {
  return __builtin_bit_cast(float, (unsigned int)s << 16);
}
// HW packed fp32->bf16 (RNE), non-volatile: compiler may schedule/CSE.
__device__ __forceinline__ unsigned int pkbf(float lo, float hi) {
  unsigned int r;
  asm("v_cvt_pk_bf16_f32 %0, %1, %2" : "=v"(r) : "v"(lo), "v"(hi));
  return r;
}

// async global->LDS, 16B per lane. LDS dest must be wave-uniform (HW adds lane*16).
__device__ __forceinline__ void lds_load16(const void* g, void* l) {
  __builtin_amdgcn_global_load_lds(
      (const __attribute__((address_space(1))) unsigned int*)g,
      (__attribute__((address_space(3))) unsigned int*)l, 16, 0, 0);
}

// ---------------------------------------------------------------------------
// cvt2: fp32 -> bf16 for Q and K in one launch (blockIdx.y picks tensor)
// ---------------------------------------------------------------------------
__global__ __launch_bounds__(256) void cvt2_f32_bf16(
    const float* __restrict__ s0, const float* __restrict__ s1,
    unsigned short* __restrict__ d0, unsigned short* __restrict__ d1, int n8) {
  const float* src = blockIdx.y ? s1 : s0;
  unsigned short* dst = blockIdx.y ? d1 : d0;
  int i = blockIdx.x * 256 + threadIdx.x;
  const int stride = gridDim.x * 256;
  for (; i < n8; i += stride) {
    float4 a = ((const float4*)src)[(size_t)i * 2];
    float4 b = ((const float4*)src)[(size_t)i * 2 + 1];
    unsigned int w[4] __attribute__((aligned(16)));
    w[0] = pkbf(a.x, a.y); w[1] = pkbf(a.z, a.w);
    w[2] = pkbf(b.x, b.y); w[3] = pkbf(b.z, b.w);
    ((uint4*)dst)[i] = *(uint4*)w;
  }
}

// ---------------------------------------------------------------------------
// qk_v4: P' = exp(scale*Q.K^T) masked->0 (bf16) + per-row partial sums.
// Tile 256(M) x 128(N), BK=64, 8 waves (4M x 2N), grid 1024 blocks,
// single-buffered, 48KB LDS, pure global_load_lds staging (0 VGPR cost).
// Measured ~116us; 6 schedule variants all land 110-120 (structural floor).
// ---------------------------------------------------------------------------
__global__ __launch_bounds__(512) void qk_v4_kernel(
    const unsigned short* __restrict__ A, const unsigned short* __restrict__ B,
    const int* __restrict__ mask, unsigned short* __restrict__ P,
    float* __restrict__ partials) {
  __shared__ __attribute__((aligned(16))) unsigned short smem[24576];  // 49152 B

  // XCD-aware bijective swizzle (NWG = 8*4*32 = 1024, %8==0)
  int flat = blockIdx.x + 8 * (blockIdx.y + 4 * blockIdx.z);
  flat = (flat % 8) * 128 + flat / 8;
  const int bx = flat % 8;            // N tile (128 cols)
  const int by = (flat / 8) % 4;      // M tile (256 rows)
  const int bh = flat / 32;

  const int t = threadIdx.x;          // 0..511
  const int lane = t & 63, wave = t >> 6;
  const int wr = wave >> 1;           // 0..3 (64-row band)
  const int wc = wave & 1;            // 0..1 (64-col band)
  const int fr = lane & 15, fq = lane >> 4;
  const int m0 = by * 256, n0 = bx * 128;

  const char* Ab = (const char*)A + ((size_t)bh * LQ + m0) * 1024;
  const char* Bb = (const char*)B + ((size_t)bh * LQ + n0) * 1024;

  // mask dtype detection (uniform)
  unsigned int orv = 0;
  {
    const unsigned int* mw = (const unsigned int*)mask;
    #pragma unroll
    for (int i = 0; i < 64; ++i) orv |= mw[i];
  }
  const bool byteMode = (orv > 1u);

  f32x4 acc[4][4];
  #pragma unroll
  for (int i = 0; i < 4; ++i)
    #pragma unroll
    for (int j = 0; j < 4; ++j) acc[i][j] = (f32x4){0.f, 0.f, 0.f, 0.f};

  char* const AsB = (char*)smem;            // A: 32768 B (256 rows x 128B)
  char* const BsB = (char*)smem + 32768;    // B: 16384 B (128 rows x 128B)

  for (int kt = 0; kt < 8; ++kt) {
    const int kb = kt * 128;    // byte offset within 1024B row
    __syncthreads();
    #pragma unroll
    for (int i = 0; i < 4; ++i) {
      const int p  = i * 8192 + t * 16;
      const int r  = p >> 7;
      const int ch = (p >> 4) & 7;
      lds_load16(Ab + (size_t)r * 1024 + kb + ((ch ^ (r & 7)) << 4),
                 AsB + i * 8192 + wave * 1024);
    }
    #pragma unroll
    for (int i = 0; i < 2; ++i) {
      const int p  = i * 8192 + t * 16;
      const int r  = p >> 7;
      const int ch = (p >> 4) & 7;
      lds_load16(Bb + (size_t)r * 1024 + kb + ((ch ^ (r & 7)) << 4),
                 BsB + i * 8192 + wave * 1024);
    }
    __syncthreads();

    #pragma unroll
    for (int kk = 0; kk < 2; ++kk) {
      short8 a[4], b[4];
      #pragma unroll
      for (int mi = 0; mi < 4; ++mi) {
        const int r  = wr * 64 + mi * 16 + fr;          // 0..255
        const int ch = (kk * 4 + fq) ^ (r & 7);
        a[mi] = *(const short8*)(AsB + r * 128 + ch * 16);
      }
      #pragma unroll
      for (int ni = 0; ni < 4; ++ni) {
        const int r  = wc * 64 + ni * 16 + fr;          // 0..127
        const int ch = (kk * 4 + fq) ^ (r & 7);
        b[ni] = *(const short8*)(BsB + r * 128 + ch * 16);
      }
      #pragma unroll
      for (int mi = 0; mi < 4; ++mi)
        #pragma unroll
        for (int ni = 0; ni < 4; ++ni)
          acc[mi][ni] = __builtin_amdgcn_mfma_f32_16x16x32_bf16(a[mi], b[ni], acc[mi][ni], 0, 0, 0);
    }
  }

  // ---- epilogue in two 128-row halves (C-stage aliases staging LDS) ----
  unsigned short* Cs = smem;   // [128][136] bf16 = 34816 B
  const size_t pbase = (size_t)bh * LQ * LQ;
  #pragma unroll
  for (int h = 0; h < 2; ++h) {
    __syncthreads();
    if ((wr >> 1) == h) {
      #pragma unroll
      for (int mi = 0; mi < 4; ++mi)
        #pragma unroll
        for (int ni = 0; ni < 4; ++ni) {
          const int col = wc * 64 + ni * 16 + fr;
          #pragma unroll
          for (int r = 0; r < 4; ++r) {
            const int rloc = (wr & 1) * 64 + mi * 16 + fq * 4 + r;
            Cs[rloc * 136 + col] = cvt_bf16(__expf(acc[mi][ni][r] * SCALE));
          }
        }
    }
    __syncthreads();
    const int rl = t >> 4;          // 0..31
    const int cl = (t & 15) * 8;    // 0..120
    #pragma unroll
    for (int rb = 0; rb < 4; ++rb) {
      const int rloc = rb * 32 + rl;
      const int rg   = m0 + h * 128 + rloc;
      const size_t gidx = pbase + (size_t)rg * LQ + (n0 + cl);
      short8 sv = *(const short8*)&Cs[rloc * 136 + cl];
      bool mk[8];
      if (byteMode) {
        const unsigned char* mb = (const unsigned char*)mask + gidx;
        uint2 w = *(const uint2*)mb;
        #pragma unroll
        for (int j = 0; j < 4; ++j) mk[j]     = ((w.x >> (8 * j)) & 255u) != 0u;
        #pragma unroll
        for (int j = 0; j < 4; ++j) mk[4 + j] = ((w.y >> (8 * j)) & 255u) != 0u;
      } else {
        int4 w0 = *(const int4*)(mask + gidx);
        int4 w1 = *(const int4*)(mask + gidx + 4);
        mk[0] = w0.x != 0; mk[1] = w0.y != 0; mk[2] = w0.z != 0; mk[3] = w0.w != 0;
        mk[4] = w1.x != 0; mk[5] = w1.y != 0; mk[6] = w1.z != 0; mk[7] = w1.w != 0;
      }
      unsigned short out[8] __attribute__((aligned(16)));
      float s = 0.f;
      #pragma unroll
      for (int j = 0; j < 8; ++j) {
        unsigned short v = mk[j] ? (unsigned short)0 : (unsigned short)sv[j];
        out[j] = v;
        s += bf2f(v);
      }
      *(short8*)(P + gidx) = *(short8*)out;
      s += __shfl_xor(s, 1); s += __shfl_xor(s, 2);
      s += __shfl_xor(s, 4); s += __shfl_xor(s, 8);
      if ((t & 15) == 0)
        partials[((size_t)bh * LQ + rg) * 8 + bx] = s;
    }
  }
}

// ---------------------------------------------------------------------------
// attn_fin: attn[row][col] = P'[row][col] * (1/rowsum)  (bf16 -> fp32)
// ---------------------------------------------------------------------------
__global__ __launch_bounds__(256) void attn_fin(
    const unsigned short* __restrict__ P, const float* __restrict__ partials,
    float* __restrict__ attn) {
  const int ch = blockIdx.x, rb64 = blockIdx.y, bh = blockIdx.z;
  const int m0 = rb64 * 64;
  __shared__ float invs[64];
  const int t = threadIdx.x;
  if (t < 64) {
    const float* pp = partials + ((size_t)bh * LQ + m0 + t) * 8;
    float s = ((pp[0] + pp[1]) + (pp[2] + pp[3])) + ((pp[4] + pp[5]) + (pp[6] + pp[7]));
    invs[t] = 1.0f / s;
  }
  __syncthreads();
  const size_t pbase = (size_t)bh * LQ * LQ;
  const int c0 = ch * 512;
  #pragma unroll
  for (int rb = 0; rb < 4; ++rb) {
    const int rloc = rb * 16 + (t >> 4);
    const int row  = m0 + rloc;
    const float inv = invs[rloc];
    const size_t base = pbase + (size_t)row * LQ + c0 + (t & 15) * 8;
    #pragma unroll
    for (int j = 0; j < 4; ++j) {
      short8 sv = *(const short8*)(P + base + j * 128);
      float4 o0, o1;
      o0.x = bf2f((unsigned short)sv[0]) * inv;
      o0.y = bf2f((unsigned short)sv[1]) * inv;
      o0.z = bf2f((unsigned short)sv[2]) * inv;
      o0.w = bf2f((unsigned short)sv[3]) * inv;
      o1.x = bf2f((unsigned short)sv[4]) * inv;
      o1.y = bf2f((unsigned short)sv[5]) * inv;
      o1.z = bf2f((unsigned short)sv[6]) * inv;
      o1.w = bf2f((unsigned short)sv[7]) * inv;
      *(float4*)(attn + base + j * 128)     = o0;
      *(float4*)(attn + base + j * 128 + 4) = o1;
    }
  }
}

// ---------------------------------------------------------------------------
// pv2: ctx = (P' . V) * invrow.  Single LDS buffer (35KB, 4 blocks/CU) +
// T14 split (round-12 proven): V loads for k+1 issued before the barrier;
// pack+ds_write of k after it (regs completed by the barrier's vmcnt drain).
// ---------------------------------------------------------------------------
__global__ __launch_bounds__(256) void pv2_kernel(
    const unsigned short* __restrict__ P, const float* __restrict__ V,
    const float* __restrict__ partials, float* __restrict__ O) {
  __shared__ __attribute__((aligned(16))) unsigned short As[8192];        // 16KB
  __shared__ __attribute__((aligned(16))) unsigned short BsV[128 * 72];   // 18KB
  __shared__ float invsL[128];

  // XCD swizzle (NWG = 4*8*32 = 1024)
  int flat = blockIdx.x + 4 * (blockIdx.y + 8 * blockIdx.z);
  flat = (flat % 8) * 128 + flat / 8;
  const int bx = flat % 4;
  const int by = (flat / 4) % 8;
  const int bh = flat / 32;

  const int t = threadIdx.x;
  const int lane = t & 63, wave = t >> 6;
  const int wr = wave >> 1, wc = wave & 1;
  const int fr = lane & 15, fq = lane >> 4;
  const int m0 = by * 128, n0 = bx * 128;

  if (t < 128) {
    const float* pp = partials + ((size_t)bh * LQ + m0 + t) * 8;
    float s = ((pp[0] + pp[1]) + (pp[2] + pp[3])) + ((pp[4] + pp[5]) + (pp[6] + pp[7]));
    invsL[t] = 1.0f / s;
  }

  const char* Ab  = (const char*)P + ((size_t)bh * LQ + m0) * 2048;
  const float* Vb = V + (size_t)bh * LQ * DK + n0;

  f32x4 acc[4][4];
  #pragma unroll
  for (int i = 0; i < 4; ++i)
    #pragma unroll
    for (int j = 0; j < 4; ++j) acc[i][j] = (f32x4){0.f, 0.f, 0.f, 0.f};

  const int g  = t >> 5;   // 0..7 (k-group of 8)
  const int nl = t & 31;   // 0..31

  float vf[8][4];          // V prefetch registers (held across compute)
  auto V_LOAD = [&](int k0) {
    #pragma unroll
    for (int i = 0; i < 8; ++i) {
      const size_t rb = (size_t)(k0 + 8 * g + i) * DK;
      #pragma unroll
      for (int jn = 0; jn < 4; ++jn)
        vf[i][jn] = Vb[rb + nl + 32 * jn];
    }
  };
  auto V_STORE = [&]() {
    #pragma unroll
    for (int jn = 0; jn < 4; ++jn) {
      const int n = nl + 32 * jn;
      uint2 w0, w1;
      w0.x = pkbf(vf[0][jn], vf[1][jn]); w0.y = pkbf(vf[2][jn], vf[3][jn]);
      w1.x = pkbf(vf[4][jn], vf[5][jn]); w1.y = pkbf(vf[6][jn], vf[7][jn]);
      *(uint2*)((char*)BsV + n * 144 + 16 * g)     = w0;
      *(uint2*)((char*)BsV + n * 144 + 16 * g + 8) = w1;
    }
  };

  V_LOAD(0);   // prologue prefetch

  for (int k0 = 0; k0 < LQ; k0 += 64) {
    __syncthreads();               // all waves done reading As/BsV(prev)
    V_STORE();                     // regs completed by previous barrier drain
    #pragma unroll
    for (int i = 0; i < 4; ++i) {
      const int p  = i * 4096 + t * 16;
      const int r  = p >> 7;
      const int ch = (p >> 4) & 7;
      const int sw = ((ch ^ (r & 7)) << 4);
      lds_load16(Ab + (size_t)r * 2048 + k0 * 2 + sw, (char*)As + wave * 1024 + i * 4096);
    }
    if (k0 + 64 < LQ) V_LOAD(k0 + 64);
    __syncthreads();               // drains vmcnt: As ready, VSTORE visible

    #pragma unroll
    for (int kk = 0; kk < 2; ++kk) {
      short8 a[4], b[4];
      #pragma unroll
      for (int mi = 0; mi < 4; ++mi) {
        const int r  = wr * 64 + mi * 16 + fr;
        const int ch = (kk * 4 + fq) ^ (r & 7);
        a[mi] = *(const short8*)((const char*)As + r * 128 + ch * 16);
      }
      #pragma unroll
      for (int ni = 0; ni < 4; ++ni) {
        const int r = wc * 64 + ni * 16 + fr;
        b[ni] = *(const short8*)((const char*)BsV + r * 144 + (kk * 4 + fq) * 16);
      }
      #pragma unroll
      for (int mi = 0; mi < 4; ++mi)
        #pragma unroll
        for (int ni = 0; ni < 4; ++ni)
          acc[mi][ni] = __builtin_amdgcn_mfma_f32_16x16x32_bf16(a[mi], b[ni], acc[mi][ni], 0, 0, 0);
    }
  }

  const size_t obase = (size_t)bh * LQ * DK;
  #pragma unroll
  for (int mi = 0; mi < 4; ++mi)
    #pragma unroll
    for (int ni = 0; ni < 4; ++ni) {
      const int col = n0 + wc * 64 + ni * 16 + fr;
      #pragma unroll
      for (int r = 0; r < 4; ++r) {
        const int rloc = wr * 64 + mi * 16 + fq * 4 + r;
        O[obase + (size_t)(m0 + rloc) * DK + col] = acc[mi][ni][r] * invsL[rloc];
      }
    }
}

// ===========================================================================
// Fallback path (round-1 kernels, no workspace needed)
// ===========================================================================
__global__ __launch_bounds__(256) void qk_mask_kernel(
    const float* __restrict__ Q, const float* __restrict__ Kmat,
    const int* __restrict__ mask, float* __restrict__ S) {
  __shared__ __attribute__((aligned(16))) unsigned short Asf[128][40];
  __shared__ __attribute__((aligned(16))) unsigned short Bsf[128][40];
  const int t = threadIdx.x;
  const int lane = t & 63, wave = t >> 6;
  const int wr = wave >> 1, wc = wave & 1;
  const int fr = lane & 15, fq = lane >> 4;
  const int bh = blockIdx.z;
  const int m0 = blockIdx.y * 128, n0 = blockIdx.x * 128;
  const float* Qb = Q + (size_t)bh * LQ * DK;
  const float* Kb = Kmat + (size_t)bh * LQ * DK;
  unsigned int orv = 0;
  { const unsigned int* mw = (const unsigned int*)mask;
    #pragma unroll
    for (int i = 0; i < 64; ++i) orv |= mw[i]; }
  const bool byteMode = (orv > 1u);
  f32x4 acc[4][4];
  #pragma unroll
  for (int i = 0; i < 4; ++i)
    #pragma unroll
    for (int j = 0; j < 4; ++j) acc[i][j] = (f32x4){0.f,0.f,0.f,0.f};
  const int sr = t >> 1, sc = (t & 1) * 16;
  for (int kd = 0; kd < DK; kd += 32) {
    __syncthreads();
    { const float4* qa = (const float4*)(Qb + (size_t)(m0+sr)*DK + kd + sc);
      float fv[16];
      #pragma unroll
      for (int i = 0; i < 4; ++i) { float4 x = qa[i];
        fv[4*i]=x.x; fv[4*i+1]=x.y; fv[4*i+2]=x.z; fv[4*i+3]=x.w; }
      unsigned short us[16] __attribute__((aligned(16)));
      #pragma unroll
      for (int i = 0; i < 16; ++i) us[i] = cvt_bf16(fv[i]);
      *(short8*)&Asf[sr][sc]   = *(short8*)&us[0];
      *(short8*)&Asf[sr][sc+8] = *(short8*)&us[8]; }
    { const float4* ka = (const float4*)(Kb + (size_t)(n0+sr)*DK + kd + sc);
      float fv[16];
      #pragma unroll
      for (int i = 0; i < 4; ++i) { float4 x = ka[i];
        fv[4*i]=x.x; fv[4*i+1]=x.y; fv[4*i+2]=x.z; fv[4*i+3]=x.w; }
      unsigned short us[16] __attribute__((aligned(16)));
      #pragma unroll
      for (int i = 0; i < 16; ++i) us[i] = cvt_bf16(fv[i]);
      *(short8*)&Bsf[sr][sc]   = *(short8*)&us[0];
      *(short8*)&Bsf[sr][sc+8] = *(short8*)&us[8]; }
    __syncthreads();
    short8 a[4], b[4];
    #pragma unroll
    for (int mi = 0; mi < 4; ++mi) a[mi] = *(const short8*)&Asf[wr*64+mi*16+fr][fq*8];
    #pragma unroll
    for (int ni = 0; ni < 4; ++ni) b[ni] = *(const short8*)&Bsf[wc*64+ni*16+fr][fq*8];
    #pragma unroll
    for (int mi = 0; mi < 4; ++mi)
      #pragma unroll
      for (int ni = 0; ni < 4; ++ni)
        acc[mi][ni] = __builtin_amdgcn_mfma_f32_16x16x32_bf16(a[mi], b[ni], acc[mi][ni], 0, 0, 0);
  }
  const size_t sbase = (size_t)bh * LQ * LQ;
  const unsigned char* mb = (const unsigned char*)mask;
  #pragma unroll
  for (int mi = 0; mi < 4; ++mi)
    #pragma unroll
    for (int ni = 0; ni < 4; ++ni) {
      const int col = n0 + wc*64 + ni*16 + fr;
      #pragma unroll
      for (int r = 0; r < 4; ++r) {
        const int row = m0 + wr*64 + mi*16 + fq*4 + r;
        const size_t idx = sbase + (size_t)row * LQ + col;
        float s = acc[mi][ni][r] * SCALE;
        const bool msk = byteMode ? (mb[idx] != 0) : (mask[idx] != 0);
        S[idx] = msk ? -1e9f : s;
      }
    }
}

__global__ __launch_bounds__(256) void softmax_kernel(float* __restrict__ A) {
  const int row = blockIdx.x;
  float4* rp = (float4*)(A + (size_t)row * LQ);
  const int t = threadIdx.x;
  float4 v = rp[t];
  float m = fmaxf(fmaxf(v.x, v.y), fmaxf(v.z, v.w));
  #pragma unroll
  for (int off = 32; off >= 1; off >>= 1) m = fmaxf(m, __shfl_xor(m, off, 64));
  __shared__ float redm[4];
  const int wv = t >> 6, ln = t & 63;
  if (ln == 0) redm[wv] = m;
  __syncthreads();
  m = fmaxf(fmaxf(redm[0], redm[1]), fmaxf(redm[2], redm[3]));
  float4 e;
  e.x = expf(v.x - m); e.y = expf(v.y - m); e.z = expf(v.z - m); e.w = expf(v.w - m);
  float s = (e.x + e.y) + (e.z + e.w);
  #pragma unroll
  for (int off = 32; off >= 1; off >>= 1) s += __shfl_xor(s, off, 64);
  __shared__ float reds2[4];
  if (ln == 0) reds2[wv] = s;
  __syncthreads();
  s = (reds2[0] + reds2[1]) + (reds2[2] + reds2[3]);
  const float inv = 1.0f / s;
  e.x *= inv; e.y *= inv; e.z *= inv; e.w *= inv;
  rp[t] = e;
}

__global__ __launch_bounds__(256) void pv_kernel(
    const float* __restrict__ P, const float* __restrict__ V, float* __restrict__ O) {
  __shared__ __attribute__((aligned(16))) unsigned short Ps[128][40];
  __shared__ __attribute__((aligned(16))) unsigned short Vtl[128][40];
  const int t = threadIdx.x;
  const int lane = t & 63, wave = t >> 6;
  const int wr = wave >> 1, wc = wave & 1;
  const int fr = lane & 15, fq = lane >> 4;
  const int bh = blockIdx.z;
  const int m0 = blockIdx.y * 128, n0 = blockIdx.x * 128;
  const float* Pb = P + (size_t)bh * LQ * LQ;
  const float* Vb = V + (size_t)bh * LQ * DK;
  f32x4 acc[4][4];
  #pragma unroll
  for (int i = 0; i < 4; ++i)
    #pragma unroll
    for (int j = 0; j < 4; ++j) acc[i][j] = (f32x4){0.f,0.f,0.f,0.f};
  const int sr = t >> 1, sc = (t & 1) * 16;
  const int kk = (t & 15) * 2, nn = (t >> 4) * 8;
  for (int k0 = 0; k0 < LQ; k0 += 32) {
    __syncthreads();
    { const float4* pa = (const float4*)(Pb + (size_t)(m0+sr)*LQ + k0 + sc);
      float fv[16];
      #pragma unroll
      for (int i = 0; i < 4; ++i) { float4 x = pa[i];
        fv[4*i]=x.x; fv[4*i+1]=x.y; fv[4*i+2]=x.z; fv[4*i+3]=x.w; }
      unsigned short us[16] __attribute__((aligned(16)));
      #pragma unroll
      for (int i = 0; i < 16; ++i) us[i] = cvt_bf16(fv[i]);
      *(short8*)&Ps[sr][sc]   = *(short8*)&us[0];
      *(short8*)&Ps[sr][sc+8] = *(short8*)&us[8]; }
    { const float* v0p = Vb + (size_t)(k0+kk)*DK + n0 + nn;
      const float* v1p = v0p + DK;
      float4 a0 = *(const float4*)v0p, a1 = *(const float4*)(v0p+4);
      float4 b0 = *(const float4*)v1p, b1 = *(const float4*)(v1p+4);
      float r0[8] = {a0.x,a0.y,a0.z,a0.w,a1.x,a1.y,a1.z,a1.w};
      float r1[8] = {b0.x,b0.y,b0.z,b0.w,b1.x,b1.y,b1.z,b1.w};
      #pragma unroll
      for (int i = 0; i < 8; ++i) {
        unsigned int pk = (unsigned int)cvt_bf16(r0[i]) | ((unsigned int)cvt_bf16(r1[i]) << 16);
        *(unsigned int*)&Vtl[nn+i][kk] = pk; } }
    __syncthreads();
    short8 a[4], b[4];
    #pragma unroll
    for (int mi = 0; mi < 4; ++mi) a[mi] = *(const short8*)&Ps[wr*64+mi*16+fr][fq*8];
    #pragma unroll
    for (int ni = 0; ni < 4; ++ni) b[ni] = *(const short8*)&Vtl[wc*64+ni*16+fr][fq*8];
    #pragma unroll
    for (int mi = 0; mi < 4; ++mi)
      #pragma unroll
      for (int ni = 0; ni < 4; ++ni)
        acc[mi][ni] = __builtin_amdgcn_mfma_f32_16x16x32_bf16(a[mi], b[ni], acc[mi][ni], 0, 0, 0);
  }
  const size_t obase = (size_t)bh * LQ * DK;
  #pragma unroll
  for (int mi = 0; mi < 4; ++mi)
    #pragma unroll
    for (int ni = 0; ni < 4; ++ni) {
      const int col = n0 + wc*64 + ni*16 + fr;
      #pragma unroll
      for (int r = 0; r < 4; ++r) {
        const int row = m0 + wr*64 + mi*16 + fq*4 + r;
        O[obase + (size_t)row * DK + col] = acc[mi][ni][r];
      }
    }
}

// ---------------------------------------------------------------------------
extern "C" void kernel_launch(void* const* d_in, const int* in_sizes, int n_in,
                              void* d_out, int out_size, void* d_ws, size_t ws_size,
                              hipStream_t stream) {
  const float* Q    = (const float*)d_in[0];
  const float* K    = (const float*)d_in[1];
  const float* V    = (const float*)d_in[2];
  const int*   mask = (const int*)d_in[3];

  float* ctx  = (float*)d_out;                  // [32,1024,512] fp32 (67.1MB)
  float* attn = ctx + (size_t)BH * LQ * DK;     // [32,1024,1024] fp32 (134MB)

  const size_t NE = (size_t)BH * LQ * DK;       // 16.78M elems
  const size_t P_BYTES  = (size_t)BH * LQ * LQ * 2;           // 67.1MB bf16
  const size_t WS_NEED  = P_BYTES + (size_t)BH * LQ * 8 * 4;  // + partials 1MB

  if (ws_size >= WS_NEED) {
    unsigned short* Pp       = (unsigned short*)d_ws;
    float*          partials = (float*)((char*)d_ws + P_BYTES);
    // Q,K bf16 live in the (dead until pv2) ctx output region
    unsigned short* Qb = (unsigned short*)ctx;
    unsigned short* Kb = Qb + NE;

    cvt2_f32_bf16<<<dim3(1024, 2), 256, 0, stream>>>(Q, K, Qb, Kb, (int)(NE / 8));
    qk_v4_kernel<<<dim3(8, 4, BH), 512, 0, stream>>>(Qb, Kb, mask, Pp, partials);
    // pv2 first (latency-bound, long tail), fin second (BW burst backfills)
    pv2_kernel<<<dim3(4, 8, BH), 256, 0, stream>>>(Pp, V, partials, ctx);
    attn_fin<<<dim3(2, 16, BH), 256, 0, stream>>>(Pp, partials, attn);
  } else {
    qk_mask_kernel<<<dim3(8, 8, BH), 256, 0, stream>>>(Q, K, mask, attn);
    softmax_kernel<<<dim3(BH * LQ), 256, 0, stream>>>(attn);
    pv_kernel<<<dim3(4, 8, BH), 256, 0, stream>>>(attn, V, ctx);
  }
}